// Round 2
// baseline (3900.978 us; speedup 1.0000x reference)
//
#include <hip/hip_runtime.h>
#include <hip/hip_bf16.h>
#include <stdint.h>

// Linear4Bit: reference dtypes are float16, which the harness delivers as
// FLOAT32 ("bfloat16 -> __hip_bfloat16*, else float*").  So:
//   x    f32 [8,2048,4096]        wq   int32 [12288,2048] (1 byte/word)
//   norm f32 [12288,1]            bias f32 [12288]        out f32 [16384,12288]
// y = x @ dequant(W)^T + bias : M=16384, N=12288, K=4096.
#define M_TOT 16384
#define N_TOT 12288
#define K_TOT 4096

typedef __bf16 bf16;
typedef __bf16 bf16x8 __attribute__((ext_vector_type(8)));
typedef float f32x4 __attribute__((ext_vector_type(4)));

typedef __attribute__((address_space(1))) const void gvoid;
typedef __attribute__((address_space(3))) void lvoid;

__device__ __forceinline__ void async_copy16(const void* g, void* l) {
    // global -> LDS direct DMA, 16B/lane; LDS dst = wave-uniform base + lane*16.
    __builtin_amdgcn_global_load_lds((gvoid*)g, (lvoid*)l, 16, 0, 0);
}

// ---------------------------------------------------------------------------
// x: f32 -> bf16 into workspace. 8 elems / thread (32B read, 16B write).
// ---------------------------------------------------------------------------
__global__ __launch_bounds__(256) void convert_x_kernel(
        const float* __restrict__ x, bf16* __restrict__ xb) {
    size_t t = (size_t)blockIdx.x * 256 + threadIdx.x;   // 8,388,608 threads
    const float4* xv = (const float4*)x;
    float4 a = xv[2 * t], b = xv[2 * t + 1];
    bf16x8 o = { (bf16)a.x, (bf16)a.y, (bf16)a.z, (bf16)a.w,
                 (bf16)b.x, (bf16)b.y, (bf16)b.z, (bf16)b.w };
    ((bf16x8*)xb)[t] = o;
}

// ---------------------------------------------------------------------------
// dequant packed nibbles -> bf16 W[N,K] into workspace. 4 words -> 8 bf16.
// low nibble = even position, high nibble = odd. w = q/15 * 2n - n.
// ---------------------------------------------------------------------------
__global__ __launch_bounds__(256) void dequant_kernel(
        const int* __restrict__ wq, const float* __restrict__ norm,
        bf16* __restrict__ wout) {
    int t = blockIdx.x * 256 + threadIdx.x;   // 6,291,456 threads
    int4 qw = ((const int4*)wq)[t];
    int row = t >> 9;                          // 512 threads per 2048-word row
    float n = norm[row];
    float s = n * (2.0f / 15.0f);
    int v[4] = {qw.x, qw.y, qw.z, qw.w};
    bf16x8 o;
#pragma unroll
    for (int u = 0; u < 4; ++u) {
        o[2*u]   = (bf16)((float)(v[u] & 15)        * s - n);
        o[2*u+1] = (bf16)((float)((v[u] >> 4) & 15) * s - n);
    }
    ((bf16x8*)wout)[t] = o;
}

// ---------------------------------------------------------------------------
// bf16 GEMM-BT (m97 structure). C[M,N] = A[M,K] * W[N,K]^T + bias, C in f32.
// 128x128 tile, BK=64, 256 threads = 4 waves (2x2), wave = 4x4 tiles of
// 16x16x32 MFMA. LDS [cb][row][8] (cb = k-chunk of 8): chunk ci = it*256+tid
// lands at LDS offset ci*16B -> lane-contiguous for global_load_lds.
// FUSED fallback (ws too small): stage A converting f32->bf16, B via nibble
// dequant, both with explicit ds_writes.
// ---------------------------------------------------------------------------
template <bool FUSED>
__global__ __launch_bounds__(256, 2) void gemm_kernel(
        const bf16*  __restrict__ Ab,    // [M,K] bf16 (pre-converted, !FUSED)
        const float* __restrict__ Af,    // [M,K] f32  (FUSED)
        const bf16*  __restrict__ Wb,    // [N,K] bf16 (pre-dequant, !FUSED)
        const int*   __restrict__ Wq,    // [N,K/2] packed words (FUSED)
        const float* __restrict__ norm,  // [N] f32 (FUSED)
        const float* __restrict__ bias,  // [N] f32
        float*       __restrict__ C)     // [M,N] f32
{
    __shared__ bf16 As[8 * 128 * 8];    // 16 KiB
    __shared__ bf16 Bs[8 * 128 * 8];    // 16 KiB
    __shared__ float Bnorm[128];

    const int tid  = threadIdx.x;
    const int m0   = blockIdx.y * 128;
    const int n0   = blockIdx.x * 128;
    const int lane = tid & 63;
    const int wave = tid >> 6;
    const int wm = wave & 1, wn = wave >> 1;    // wave covers 64x64
    const int lm = lane & 15, q = lane >> 4;    // MFMA lane coords

    if (FUSED) {
        if (tid < 128) Bnorm[tid] = norm[n0 + tid];
        __syncthreads();
    }

    f32x4 acc[4][4];
#pragma unroll
    for (int i = 0; i < 4; ++i)
#pragma unroll
        for (int j = 0; j < 4; ++j) acc[i][j] = (f32x4){0.f, 0.f, 0.f, 0.f};

    for (int k0 = 0; k0 < K_TOT; k0 += 64) {
#pragma unroll
        for (int it = 0; it < 4; ++it) {
            int ci = it * 256 + tid;
            int cb = ci >> 7, row = ci & 127;
            if (!FUSED) {
                async_copy16(Ab + (size_t)(m0 + row) * K_TOT + k0 + cb * 8,
                             &As[ci * 8]);
            } else {
                const float4* p = (const float4*)(Af + (size_t)(m0 + row) * K_TOT
                                                  + k0 + cb * 8);
                float4 a = p[0], b = p[1];
                bf16x8 o = { (bf16)a.x, (bf16)a.y, (bf16)a.z, (bf16)a.w,
                             (bf16)b.x, (bf16)b.y, (bf16)b.z, (bf16)b.w };
                *(bf16x8*)&As[ci * 8] = o;
            }
        }
#pragma unroll
        for (int it = 0; it < 4; ++it) {
            int ci = it * 256 + tid;
            int cb = ci >> 7, row = ci & 127;
            if (!FUSED) {
                async_copy16(Wb + (size_t)(n0 + row) * K_TOT + k0 + cb * 8,
                             &Bs[ci * 8]);
            } else {
                int4 qw = *(const int4*)(Wq + (size_t)(n0 + row) * (K_TOT / 2)
                                         + (k0 >> 1) + cb * 4);
                float n = Bnorm[row];
                float s = n * (2.0f / 15.0f);
                int v[4] = {qw.x, qw.y, qw.z, qw.w};
                bf16x8 o;
#pragma unroll
                for (int u = 0; u < 4; ++u) {
                    o[2*u]   = (bf16)((float)(v[u] & 15)        * s - n);
                    o[2*u+1] = (bf16)((float)((v[u] >> 4) & 15) * s - n);
                }
                *(bf16x8*)&Bs[ci * 8] = o;
            }
        }
        __syncthreads();   // drains vmcnt (async LDS-DMA) + lgkmcnt

        // ---- compute: 2 k-steps of 32, 16 MFMA each ----
#pragma unroll
        for (int ks = 0; ks < 2; ++ks) {
            bf16x8 af[4], bfr[4];
            int cb = ks * 4 + q;
#pragma unroll
            for (int i = 0; i < 4; ++i) {
                int row = wm * 64 + i * 16 + lm;
                af[i] = *(const bf16x8*)&As[(cb * 128 + row) * 8];
            }
#pragma unroll
            for (int j = 0; j < 4; ++j) {
                int row = wn * 64 + j * 16 + lm;
                bfr[j] = *(const bf16x8*)&Bs[(cb * 128 + row) * 8];
            }
#pragma unroll
            for (int i = 0; i < 4; ++i)
#pragma unroll
                for (int j = 0; j < 4; ++j)
                    acc[i][j] = __builtin_amdgcn_mfma_f32_16x16x32_bf16(
                        af[i], bfr[j], acc[i][j], 0, 0, 0);
        }
        __syncthreads();
    }

    // ---- epilogue: D[m = q*4+r][n = lm] per 16x16 tile; + bias, f32 out ----
    float bj[4];
#pragma unroll
    for (int j = 0; j < 4; ++j)
        bj[j] = bias[n0 + wn * 64 + j * 16 + lm];
#pragma unroll
    for (int i = 0; i < 4; ++i) {
#pragma unroll
        for (int r = 0; r < 4; ++r) {
            size_t row  = (size_t)(m0 + wm * 64 + i * 16 + q * 4 + r);
            size_t base = row * N_TOT + n0 + wn * 64 + lm;
#pragma unroll
            for (int j = 0; j < 4; ++j)
                C[base + j * 16] = acc[i][j][r] + bj[j];
        }
    }
}

extern "C" void kernel_launch(void* const* d_in, const int* in_sizes, int n_in,
                              void* d_out, int out_size, void* d_ws, size_t ws_size,
                              hipStream_t stream) {
    const float* x    = (const float*)d_in[0];
    const int*   wq   = (const int*)d_in[1];
    const float* norm = (const float*)d_in[2];
    const float* bias = (const float*)d_in[3];
    float* out = (float*)d_out;

    const size_t WBYTES = (size_t)N_TOT * K_TOT * sizeof(bf16);  //  96 MiB
    const size_t XBYTES = (size_t)M_TOT * K_TOT * sizeof(bf16);  // 128 MiB
    dim3 grid(N_TOT / 128, M_TOT / 128);   // 96 x 128 = 12288 blocks

    if (ws_size >= WBYTES + XBYTES) {
        bf16* wdq = (bf16*)d_ws;
        bf16* xb  = (bf16*)((char*)d_ws + WBYTES);
        dequant_kernel<<<(N_TOT * (K_TOT / 2) / 4) / 256, 256, 0, stream>>>(
            wq, norm, wdq);
        convert_x_kernel<<<(M_TOT * K_TOT / 8) / 256, 256, 0, stream>>>(x, xb);
        gemm_kernel<false><<<grid, 256, 0, stream>>>(xb, nullptr, wdq, nullptr,
                                                     nullptr, bias, out);
    } else {
        // workspace too small: fully fused staging (f32 convert + nibble dequant)
        gemm_kernel<true><<<grid, 256, 0, stream>>>(nullptr, x, nullptr, wq,
                                                    norm, bias, out);
    }
}